// Round 1
// baseline (395.642 us; speedup 1.0000x reference)
//
#include <hip/hip_runtime.h>
#include <math.h>

#define BB 8
#define TT 4096
#define DDIM 512
#define KK 4096
#define NN (BB*TT)
#define EPS 0.05f

typedef __attribute__((ext_vector_type(8))) short bf16x8;
typedef __attribute__((ext_vector_type(4))) float f32x4;

__device__ __forceinline__ void async16(void* lds, const void* g) {
  __builtin_amdgcn_global_load_lds((const __attribute__((address_space(1))) void*)g,
                                   (__attribute__((address_space(3))) void*)lds, 16, 0, 0);
}

__device__ __forceinline__ unsigned pk_bf16(float a, float b) {
  unsigned ua = __float_as_uint(a); ua += 0x7FFFu + ((ua >> 16) & 1u);
  unsigned ub = __float_as_uint(b); ub += 0x7FFFu + ((ub >> 16) & 1u);
  return (ua >> 16) | (ub & 0xFFFF0000u);
}

// ---------- prep: row sum-sq (esq or inv2=2/norm) + bf16 (RTNE) conversion ----------
__global__ __launch_bounds__(256) void prep_kernel(const float* __restrict__ src,
                                                   short* __restrict__ dst16,
                                                   float* __restrict__ outv, int mode) {
  int r = blockIdx.x * 4 + (threadIdx.x >> 6);
  int lane = threadIdx.x & 63;
  const float4* row4 = (const float4*)(src + (size_t)r * DDIM);
  float4 v0 = row4[lane];
  float4 v1 = row4[lane + 64];
  uint2 p0, p1;
  p0.x = pk_bf16(v0.x, v0.y); p0.y = pk_bf16(v0.z, v0.w);
  p1.x = pk_bf16(v1.x, v1.y); p1.y = pk_bf16(v1.z, v1.w);
  *(uint2*)(dst16 + (size_t)r * DDIM + lane * 4) = p0;
  *(uint2*)(dst16 + (size_t)r * DDIM + 256 + lane * 4) = p1;
  float ss = v0.x*v0.x + v0.y*v0.y + v0.z*v0.z + v0.w*v0.w
           + v1.x*v1.x + v1.y*v1.y + v1.z*v1.z + v1.w*v1.w;
  #pragma unroll
  for (int off = 32; off; off >>= 1) ss += __shfl_down(ss, off);
  if (lane == 0) outv[r] = mode ? 2.0f / fmaxf(sqrtf(ss), 1e-12f) : ss;
}

// ---------- main MFMA pass: 256 rows x 1024 codes per block ----------
// 8-phase-style schedule: BK=32 quad-buffered LDS, counted vmcnt(8) (never 0
// in steady state), raw s_barrier (no compiler vmcnt(0) drain), setprio around
// MFMA clusters, sigma-swizzled LDS (pre-swizzled global source, linear
// global_load_lds dest, swizzled ds_read).
// grid 512: bid>>2 = m-block (256 rows), bid&3 = k-quarter (1024 codes)
__global__ __launch_bounds__(512, 2) void vq_mfma(const short* __restrict__ xb,
                                                  const short* __restrict__ eb,
                                                  const float* __restrict__ esq,
                                                  const float* __restrict__ inv2,
                                                  float4* __restrict__ top2) {
  // 4 buffers x (256 rows x 32 k) bf16 for A and B  (64 KiB + 64 KiB)
  __shared__ __attribute__((aligned(16))) short As[4 * 256 * 32];
  __shared__ __attribute__((aligned(16))) short Bs[4 * 256 * 32];
  __shared__ float rS1[4][256];
  __shared__ float rS2[4][256];
  __shared__ int   rI1[4][256];
  __shared__ __attribute__((aligned(16))) float invLds[256];
  __shared__ float esqLds[1024];   // pre-negated

  const int tid = threadIdx.x;
  const int lane = tid & 63;
  const int w = tid >> 6;          // 0..7
  const int wr = w >> 2;           // row half (0..1):   rows wr*128..+128
  const int wc = w & 3;            // code quarter (0..3): codes wc*64..+64
  const int q = lane >> 4, c16 = lane & 15;

  const int mb = blockIdx.x >> 2;
  const int kq = blockIdx.x & 3;
  const int n0 = mb * 256;
  const int kbase = kq * 1024;

  // ---- setup: esq (negated) and inv2 slices into LDS (keeps epilogue VMEM-free) ----
  if (tid < 256) invLds[tid] = inv2[n0 + tid];
  esqLds[tid]       = -esq[kbase + tid];
  esqLds[tid + 512] = -esq[kbase + 512 + tid];
  __syncthreads();

  // ---- staging constants ----
  // LDS linear slot of this thread within its wave's 1KB: pair p = w*8+(lane>>3)
  // (rows 2p,2p+1), slot s = lane&7. Physical slot s = ((r&1)*4 + q) ^ (p&7),
  // so the thread fetches row parity sb, k-chunk sq with sb*4+sq = s ^ (p&7).
  const int sxq = (lane & 7) ^ (lane >> 3);
  const int sb  = sxq >> 2;
  const int sq  = sxq & 3;
  const int srow = w * 16 + (lane >> 3) * 2 + sb;          // row within 128-half
  const short* gA = xb + (size_t)(n0 + srow) * DDIM + sq * 8;
  const short* gB = eb + (size_t)(kbase + srow) * DDIM + sq * 8;
  short* sA = As + w * 512;   // wave-uniform LDS stage base (shorts)
  short* sB = Bs + w * 512;

  // ---- fragment read offsets (shorts); sigma constant per thread ----
  const int sigma = (((c16 & 1) * 4 + q) ^ (c16 >> 1));
  const int aoff = wr * 4096 + (c16 >> 1) * 64 + sigma * 8;  // + buf*8192 + ti*512
  const int boff = wc * 2048 + (c16 >> 1) * 64 + sigma * 8;  // + buf*8192 + tj*512

  // stage step u3 (t = u3&15, c = u3>>4) into buffer u3&3 (2 loads A, 2 loads B)
#define STAGE_A(u3) do { int t_ = (u3) & 15, b_ = (u3) & 3;              \
    const short* g_ = gA + t_ * 32;                                      \
    async16(sA + b_ * 8192,        g_);                                  \
    async16(sA + b_ * 8192 + 4096, g_ + 128 * DDIM); } while (0)
#define STAGE_B(u3) do { int c_ = (u3) >> 4, t_ = (u3) & 15, b_ = (u3) & 3; \
    const short* g_ = gB + (size_t)c_ * (256 * DDIM) + t_ * 32;          \
    async16(sB + b_ * 8192,        g_);                                  \
    async16(sB + b_ * 8192 + 4096, g_ + 128 * DDIM); } while (0)

  // ---- prologue: steps 0,1,2 in flight; wait for step 0 only ----
  STAGE_A(0); STAGE_B(0);
  STAGE_A(1); STAGE_B(1);
  STAGE_A(2); STAGE_B(2);
  asm volatile("s_waitcnt vmcnt(8)" ::: "memory");
  asm volatile("s_barrier" ::: "memory");

  for (int c = 0; c < 4; ++c) {
    f32x4 acc[8][4];
    #pragma unroll
    for (int ti = 0; ti < 8; ++ti)
      #pragma unroll
      for (int tj = 0; tj < 4; ++tj)
        acc[ti][tj] = (f32x4){0.f, 0.f, 0.f, 0.f};

    #pragma unroll 4
    for (int t = 0; t < 16; ++t) {
      const int u = c * 16 + t;
      const short* Ab = As + (u & 3) * 8192;
      const short* Bb = Bs + (u & 3) * 8192;
      // ---------- phase A: ti 0-3 x tj 0-3 ----------
      bf16x8 af0[4], bfr[4];
      #pragma unroll
      for (int ti = 0; ti < 4; ++ti)
        af0[ti] = *(const bf16x8*)(Ab + ti * 512 + aoff);
      #pragma unroll
      for (int tj = 0; tj < 4; ++tj)
        bfr[tj] = *(const bf16x8*)(Bb + tj * 512 + boff);
      if (u < 61) STAGE_A(u + 3);
      asm volatile("s_barrier" ::: "memory");
      __builtin_amdgcn_s_setprio(1);
      #pragma unroll
      for (int ti = 0; ti < 4; ++ti)
        #pragma unroll
        for (int tj = 0; tj < 4; ++tj)
          acc[ti][tj] = __builtin_amdgcn_mfma_f32_16x16x32_bf16(af0[ti], bfr[tj], acc[ti][tj], 0, 0, 0);
      __builtin_amdgcn_s_setprio(0);
      asm volatile("s_barrier" ::: "memory");
      // ---------- phase B: ti 4-7 x tj 0-3 ----------
      bf16x8 af1[4];
      #pragma unroll
      for (int ti = 0; ti < 4; ++ti)
        af1[ti] = *(const bf16x8*)(Ab + (ti + 4) * 512 + aoff);
      if (u < 61) STAGE_B(u + 3);
      // counted wait: ensure step u+1's 4 loads done; leave steps u+2,u+3 (8) in flight
      if (u < 61)       asm volatile("s_waitcnt vmcnt(8)" ::: "memory");
      else if (u == 61) asm volatile("s_waitcnt vmcnt(4)" ::: "memory");
      else if (u == 62) asm volatile("s_waitcnt vmcnt(0)" ::: "memory");
      asm volatile("s_barrier" ::: "memory");
      __builtin_amdgcn_s_setprio(1);
      #pragma unroll
      for (int ti = 0; ti < 4; ++ti)
        #pragma unroll
        for (int tj = 0; tj < 4; ++tj)
          acc[ti + 4][tj] = __builtin_amdgcn_mfma_f32_16x16x32_bf16(af1[ti], bfr[tj], acc[ti + 4][tj], 0, 0, 0);
      __builtin_amdgcn_s_setprio(0);
      asm volatile("s_barrier" ::: "memory");
    }

    // ---------- epilogue for this 256-code tile ----------
    float nes[4];
    #pragma unroll
    for (int tj = 0; tj < 4; ++tj)
      nes[tj] = esqLds[c * 256 + wc * 64 + tj * 16 + c16];
    const int colbase = kbase + c * 256 + wc * 64 + c16;
    #pragma unroll
    for (int ti = 0; ti < 8; ++ti) {
      f32x4 iv4 = *(const f32x4*)&invLds[wr * 128 + ti * 16 + q * 4];
      #pragma unroll
      for (int r = 0; r < 4; ++r) {
        const float iv = iv4[r];
        float a1 = -3e38f, a2 = -3e38f; int ai = 0;
        #pragma unroll
        for (int tj = 0; tj < 4; ++tj) {
          float sc = fmaf(acc[ti][tj][r], iv, nes[tj]);
          float mn = fminf(sc, a1);
          a2 = fmaxf(a2, mn);
          if (sc > a1) { a1 = sc; ai = colbase + tj * 16; }
        }
        // reduce across the 16 lanes (c16) sharing this row
        #pragma unroll
        for (int off = 1; off < 16; off <<= 1) {
          float b1 = __shfl_xor(a1, off);
          float b2 = __shfl_xor(a2, off);
          int   bi = __shfl_xor(ai, off);
          float mn = fminf(a1, b1);
          a2 = fmaxf(fmaxf(a2, b2), mn);
          if (b1 > a1) { a1 = b1; ai = bi; }
        }
        if (c16 == 0) {
          const int row = wr * 128 + ti * 16 + q * 4 + r;
          if (c == 0) {
            rS1[wc][row] = a1; rS2[wc][row] = a2; rI1[wc][row] = ai;
          } else {
            float o1 = rS1[wc][row], o2 = rS2[wc][row]; int oi = rI1[wc][row];
            float mn = fminf(a1, o1);
            o2 = fmaxf(fmaxf(a2, o2), mn);
            if (a1 > o1) { o1 = a1; oi = ai; }
            rS1[wc][row] = o1; rS2[wc][row] = o2; rI1[wc][row] = oi;
          }
        }
      }
    }
  }
#undef STAGE_A
#undef STAGE_B

  __syncthreads();
  if (tid < 256) {
    float a1 = rS1[0][tid], a2 = rS2[0][tid]; int ai = rI1[0][tid];
    #pragma unroll
    for (int g = 1; g < 4; ++g) {
      float b1 = rS1[g][tid], b2 = rS2[g][tid]; int bi = rI1[g][tid];
      float mn = fminf(a1, b1);
      a2 = fmaxf(fmaxf(a2, b2), mn);
      if (b1 > a1 || (b1 == a1 && bi < ai)) { a1 = b1; ai = bi; }
    }
    top2[(size_t)kq * NN + n0 + tid] = make_float4(a1, __int_as_float(ai), a2, 0.f);
  }
}

// ---------- finalize: merge 4 k-quarters, write idx, flag small-margin rows ----------
__global__ __launch_bounds__(256) void finalize_kernel(const float4* __restrict__ top2,
                                                       float* __restrict__ out_ind,
                                                       int* __restrict__ flags,
                                                       int* __restrict__ list,
                                                       int* __restrict__ cnt) {
  int row = blockIdx.x * 256 + threadIdx.x;
  float a1 = -3e38f, a2 = -3e38f; int ai = 0;
  #pragma unroll
  for (int kq = 0; kq < 4; ++kq) {
    float4 t = top2[(size_t)kq * NN + row];
    float b1 = t.x, b2 = t.z; int bi = __float_as_int(t.y);
    float mn = fminf(a1, b1);
    a2 = fmaxf(fmaxf(a2, b2), mn);
    if (b1 > a1 || (b1 == a1 && bi < ai)) { a1 = b1; ai = bi; }
  }
  out_ind[row] = (float)ai;
  if (a1 - a2 < EPS) {
    int p = atomicAdd(cnt, 1);
    list[p] = row;
    flags[row] = p + 1;
  } else {
    flags[row] = 0;
  }
}

// ---------- cleanup: exact fp32 rescore of flagged rows (split 8 k-chunks) ----------
__global__ __launch_bounds__(256) void cleanup_kernel(const float* __restrict__ x,
                                                      const float* __restrict__ embed,
                                                      const float* __restrict__ esq,
                                                      const float* __restrict__ inv2,
                                                      const int* __restrict__ list,
                                                      const int* __restrict__ cnt,
                                                      float2* __restrict__ exact) {
  __shared__ float xr[DDIM];
  __shared__ float red_s[4];
  __shared__ int   red_i[4];
  const int rs = blockIdx.x & 31, kc = blockIdx.x >> 5;
  const int tid = threadIdx.x;
  const int lane = tid & 63, wid = tid >> 6;
  const int n = *cnt;
  for (int ii = rs; ii < n; ii += 32) {
    const int row = list[ii];
    __syncthreads();
    if (tid < 128) *(float4*)&xr[tid * 4] = *(const float4*)&x[(size_t)row * DDIM + tid * 4];
    __syncthreads();
    const float iv = inv2[row];
    float bs = -3e38f; int bi = 0;
    for (int cc = 0; cc < 2; ++cc) {
      const int code = kc * 512 + cc * 256 + tid;
      const float4* er = (const float4*)&embed[(size_t)code * DDIM];
      float acc = 0.f;
      for (int d = 0; d < DDIM / 4; ++d) {
        float4 e4 = er[d];
        float4 x4 = *(const float4*)&xr[d * 4];
        acc += x4.x * e4.x + x4.y * e4.y + x4.z * e4.z + x4.w * e4.w;
      }
      float sc = fmaf(acc, iv, -esq[code]);
      if (sc > bs || (sc == bs && code < bi)) { bs = sc; bi = code; }
    }
    #pragma unroll
    for (int off = 1; off < 64; off <<= 1) {
      float b1 = __shfl_xor(bs, off);
      int   b2 = __shfl_xor(bi, off);
      if (b1 > bs || (b1 == bs && b2 < bi)) { bs = b1; bi = b2; }
    }
    if (lane == 0) { red_s[wid] = bs; red_i[wid] = bi; }
    __syncthreads();
    if (tid == 0) {
      for (int ww = 1; ww < 4; ++ww)
        if (red_s[ww] > red_s[0] || (red_s[ww] == red_s[0] && red_i[ww] < red_i[0])) {
          red_s[0] = red_s[ww]; red_i[0] = red_i[ww];
        }
      exact[(size_t)ii * 8 + kc] = make_float2(red_s[0], (float)red_i[0]);
    }
  }
}

// ---------- gather + transpose (merges exact results for flagged rows) ----------
__global__ __launch_bounds__(256) void gather_kernel(const float* __restrict__ embed,
                                                     const int* __restrict__ flags,
                                                     const float2* __restrict__ exact,
                                                     float* __restrict__ out_ind,
                                                     float* __restrict__ out_q) {
  __shared__ int lidx[64];
  __shared__ float trans[64 * 65];
  const int n0 = blockIdx.x * 64;
  const int tid = threadIdx.x;
  if (tid < 64) {
    const int row = n0 + tid;
    const int f = flags[row];
    int idx;
    if (f) {
      float bsv = -3e38f; int bi = 0;
      const float2* e8 = &exact[(size_t)(f - 1) * 8];
      #pragma unroll
      for (int k = 0; k < 8; ++k) {
        float2 t = e8[k];
        int ci = (int)t.y;
        if (t.x > bsv || (t.x == bsv && ci < bi)) { bsv = t.x; bi = ci; }
      }
      idx = bi;
      out_ind[row] = (float)idx;
    } else {
      idx = (int)out_ind[row];
    }
    lidx[tid] = idx;
  }
  __syncthreads();
  const int bb = n0 >> 12;
  const int t0 = n0 & (TT - 1);
  const int w = tid >> 6, lane = tid & 63;
  for (int d0 = 0; d0 < DDIM; d0 += 64) {
    if (d0) __syncthreads();
    #pragma unroll
    for (int qq = 0; qq < 16; ++qq) {
      int tt2 = w * 16 + qq;
      int e = lidx[tt2];
      trans[lane * 65 + tt2] = embed[(size_t)e * DDIM + d0 + lane];
    }
    __syncthreads();
    #pragma unroll
    for (int qq = 0; qq < 4; ++qq) {
      int dl = (tid >> 4) * 4 + qq;
      int t4 = (tid & 15) * 4;
      float4 o;
      o.x = trans[dl * 65 + t4 + 0];
      o.y = trans[dl * 65 + t4 + 1];
      o.z = trans[dl * 65 + t4 + 2];
      o.w = trans[dl * 65 + t4 + 3];
      *(float4*)&out_q[((size_t)bb * DDIM + d0 + dl) * TT + t0 + t4] = o;
    }
  }
}

extern "C" void kernel_launch(void* const* d_in, const int* in_sizes, int n_in,
                              void* d_out, int out_size, void* d_ws, size_t ws_size,
                              hipStream_t stream) {
  const float* x     = (const float*)d_in[0];
  const float* embed = (const float*)d_in[1];
  char* ws = (char*)d_ws;
  short* xb      = (short*)(ws);                         // 33,554,432 B
  short* eb      = (short*)(ws + 33554432);              //  4,194,304 B
  float* esq     = (float*)(ws + 37748736);              //     16,384 B
  float* inv2    = (float*)(ws + 37765120);              //    131,072 B
  float4* top2   = (float4*)(ws + 37896192);             //  2,097,152 B
  int* list      = (int*)(ws + 39993344);                //    131,072 B
  int* flags     = (int*)(ws + 40124416);                //    131,072 B
  float2* exact  = (float2*)(ws + 40255488);             //  2,097,152 B
  int* cnt       = (int*)(ws + 42352640);                //          4 B

  float* out_ind = (float*)d_out;
  float* out_q   = out_ind + NN;

  prep_kernel<<<KK / 4, 256, 0, stream>>>(embed, eb, esq, 0);
  prep_kernel<<<NN / 4, 256, 0, stream>>>(x, xb, inv2, 1);
  hipMemsetAsync(cnt, 0, 4, stream);
  vq_mfma<<<512, 512, 0, stream>>>(xb, eb, esq, inv2, top2);
  finalize_kernel<<<NN / 256, 256, 0, stream>>>(top2, out_ind, flags, list, cnt);
  cleanup_kernel<<<256, 256, 0, stream>>>(x, embed, esq, inv2, list, cnt, exact);
  gather_kernel<<<NN / 64, 256, 0, stream>>>(embed, flags, exact, out_ind, out_q);
}

// Round 2
// 317.794 us; speedup vs baseline: 1.2450x; 1.2450x over previous
//
#include <hip/hip_runtime.h>
#include <math.h>

#define BB 8
#define TT 4096
#define DDIM 512
#define KK 4096
#define NN (BB*TT)
#define EPS 0.05f

typedef __attribute__((ext_vector_type(8))) short bf16x8;
typedef __attribute__((ext_vector_type(4))) float f32x4;

__device__ __forceinline__ void async16(void* lds, const void* g) {
  __builtin_amdgcn_global_load_lds((const __attribute__((address_space(1))) void*)g,
                                   (__attribute__((address_space(3))) void*)lds, 16, 0, 0);
}

__device__ __forceinline__ unsigned pk_bf16(float a, float b) {
  unsigned ua = __float_as_uint(a); ua += 0x7FFFu + ((ua >> 16) & 1u);
  unsigned ub = __float_as_uint(b); ub += 0x7FFFu + ((ub >> 16) & 1u);
  return (ua >> 16) | (ub & 0xFFFF0000u);
}

// ---------- prep: row sum-sq (esq or inv2=2/norm) + bf16 (RTNE) conversion ----------
__global__ __launch_bounds__(256) void prep_kernel(const float* __restrict__ src,
                                                   short* __restrict__ dst16,
                                                   float* __restrict__ outv, int mode) {
  int r = blockIdx.x * 4 + (threadIdx.x >> 6);
  int lane = threadIdx.x & 63;
  const float4* row4 = (const float4*)(src + (size_t)r * DDIM);
  float4 v0 = row4[lane];
  float4 v1 = row4[lane + 64];
  uint2 p0, p1;
  p0.x = pk_bf16(v0.x, v0.y); p0.y = pk_bf16(v0.z, v0.w);
  p1.x = pk_bf16(v1.x, v1.y); p1.y = pk_bf16(v1.z, v1.w);
  *(uint2*)(dst16 + (size_t)r * DDIM + lane * 4) = p0;
  *(uint2*)(dst16 + (size_t)r * DDIM + 256 + lane * 4) = p1;
  float ss = v0.x*v0.x + v0.y*v0.y + v0.z*v0.z + v0.w*v0.w
           + v1.x*v1.x + v1.y*v1.y + v1.z*v1.z + v1.w*v1.w;
  #pragma unroll
  for (int off = 32; off; off >>= 1) ss += __shfl_down(ss, off);
  if (lane == 0) outv[r] = mode ? 2.0f / fmaxf(sqrtf(ss), 1e-12f) : ss;
}

// ---------- main MFMA pass: A-resident design ----------
// 256 blocks (1/CU), 512 threads (8 waves, 2 row-halves x 4 code-quarters).
// A (128 rows x 512 dims bf16, 128 KiB) staged ONCE into LDS; the codebook
// streams through a 2 x 16 KiB double buffer (256 codes x 32 dims per chunk).
// One __syncthreads per K-step; stage issued at step top so the pre-barrier
// vmcnt(0) drain finds L2-hit loads already returned. Each block scans ALL
// 4096 codes -> per-row top-2 kept in registers, merged once at the end;
// finalize pass eliminated (this kernel writes out_ind/flags/list directly).
__global__ __launch_bounds__(512, 2) void vq_mfma(const short* __restrict__ xb,
                                                  const short* __restrict__ eb,
                                                  const float* __restrict__ esq,
                                                  const float* __restrict__ inv2,
                                                  float* __restrict__ out_ind,
                                                  int* __restrict__ flags,
                                                  int* __restrict__ list,
                                                  int* __restrict__ cnt) {
  __shared__ __attribute__((aligned(16))) short As[128 * 512];   // 131072 B
  __shared__ __attribute__((aligned(16))) short Bs[2 * 256 * 32]; // 32768 B

  const int tid = threadIdx.x;
  const int lane = tid & 63;
  const int w = tid >> 6;          // 0..7
  const int wr = w >> 2;           // row half (0..1): rows wr*64..+64
  const int wc = w & 3;            // code quarter within 256-tile
  const int q = lane >> 4, c16 = lane & 15;
  const int n0 = blockIdx.x * 128;

  // ---- A stage (once): LDS row j*8+w; phys 16B-chunk `lane` holds global chunk lane^w
  // (per-row XOR swizzle: logical chunk c stored at physical c ^ (row&7))
  #pragma unroll
  for (int j = 0; j < 16; ++j)
    async16(As + (j * 8 + w) * 512,
            xb + (size_t)(n0 + j * 8 + w) * 512 + (lane ^ w) * 8);

  // ---- B stage thread constants (pair-window swizzle, same sigma family as before)
  // window p = k*64 + w*8 + (lane>>3); phys slot ps = lane&7 holds (b,c) with
  // b*4+c = ps ^ (p&7); dest = uniform + lane*16 (global_load_lds requirement).
  const int x = (lane & 7) ^ (lane >> 3);
  const int scode = w * 16 + (lane >> 3) * 2 + (x >> 2);   // k=0 local code
  const short* gB = eb + (size_t)scode * 512 + (x & 3) * 8;
  short* sB0 = Bs + w * 512;                                // + k*4096 + buf*8192
  async16(sB0,        gB);                // chunk g=0, k=0 (codes 0..127)
  async16(sB0 + 4096, gB + 128 * 512);    // chunk g=0, k=1 (codes 128..255)

  // ---- fragment read constants ----
  const int sigB8 = ((((c16 & 1) << 2) | q) ^ ((c16 >> 1) & 7)) * 8;
  const int brow0 = (wc * 32 + (c16 >> 1)) * 64 + sigB8;    // + tj*512 + buf*8192
  const int arow0 = (wr * 64 + c16) * 512;                  // + ti*8192 + ach

  // inv2 values for my 16 row-slots (held in regs for whole kernel)
  f32x4 iv4[4];
  #pragma unroll
  for (int ti = 0; ti < 4; ++ti)
    iv4[ti] = *(const f32x4*)&inv2[n0 + wr * 64 + ti * 16 + q * 4];

  float s1[16], s2v[16];
  int   i1[16];
  #pragma unroll
  for (int s = 0; s < 16; ++s) { s1[s] = -3e38f; s2v[s] = -3e38f; i1[s] = 0; }

  __syncthreads();   // A + B chunk 0 landed

  for (int ct = 0; ct < 16; ++ct) {
    float nes[4];
    #pragma unroll
    for (int tj = 0; tj < 4; ++tj)
      nes[tj] = -esq[ct * 256 + wc * 64 + tj * 16 + c16];
    f32x4 acc[4][4];
    #pragma unroll
    for (int ti = 0; ti < 4; ++ti)
      #pragma unroll
      for (int tj = 0; tj < 4; ++tj) acc[ti][tj] = (f32x4){0.f, 0.f, 0.f, 0.f};

    #pragma unroll 2
    for (int s = 0; s < 16; ++s) {
      const int g = ct * 16 + s;
      // stage next chunk first: full step of MFMA covers its L2 latency
      if (g < 255) {
        const int gn = g + 1;
        const short* src = gB + (size_t)(gn >> 4) * (256 * 512) + (gn & 15) * 32;
        short* dst = Bs + ((gn & 1) << 13) + w * 512;
        async16(dst,        src);
        async16(dst + 4096, src + 128 * 512);
      }
      const short* Ap = As + arow0;
      const short* Bp = Bs + ((g & 1) << 13) + brow0;
      const int ach = ((s * 4 + q) ^ (c16 & 7)) * 8;
      bf16x8 af[4], bf[4];
      #pragma unroll
      for (int ti = 0; ti < 4; ++ti)
        af[ti] = *(const bf16x8*)(Ap + ti * 8192 + ach);
      #pragma unroll
      for (int tj = 0; tj < 4; ++tj)
        bf[tj] = *(const bf16x8*)(Bp + tj * 512);
      __builtin_amdgcn_s_setprio(1);
      #pragma unroll
      for (int ti = 0; ti < 4; ++ti)
        #pragma unroll
        for (int tj = 0; tj < 4; ++tj)
          acc[ti][tj] = __builtin_amdgcn_mfma_f32_16x16x32_bf16(af[ti], bf[tj], acc[ti][tj], 0, 0, 0);
      __builtin_amdgcn_s_setprio(0);
      __syncthreads();
    }

    // ---------- epilogue for this 256-code tile (registers only) ----------
    const int colbase = ct * 256 + wc * 64 + c16;
    #pragma unroll
    for (int ti = 0; ti < 4; ++ti)
      #pragma unroll
      for (int r = 0; r < 4; ++r) {
        const int slot = ti * 4 + r;
        const float iv = iv4[ti][r];
        #pragma unroll
        for (int tj = 0; tj < 4; ++tj) {
          float sc = fmaf(acc[ti][tj][r], iv, nes[tj]);
          float mn = fminf(sc, s1[slot]);
          s2v[slot] = fmaxf(s2v[slot], mn);
          if (sc > s1[slot]) { s1[slot] = sc; i1[slot] = colbase + tj * 16; }
        }
      }
  }

  // ---------- final merge: 16 lanes -> 4 wc-waves -> write results ----------
  // Bs is dead now (last chunk g=255 lived in buffer 1, bytes 16384+; we reuse
  // buffer 0's bytes 0..6143 — all staging drained by the last __syncthreads).
  float* rS1 = (float*)Bs;           // [4][128]
  float* rS2 = rS1 + 512;
  int*   rI1 = (int*)(rS2 + 512);
  #pragma unroll
  for (int slot = 0; slot < 16; ++slot) {
    float a1 = s1[slot], a2 = s2v[slot]; int ai = i1[slot];
    #pragma unroll
    for (int off = 1; off < 16; off <<= 1) {
      float b1 = __shfl_xor(a1, off);
      float b2 = __shfl_xor(a2, off);
      int   bi = __shfl_xor(ai, off);
      float mn = fminf(a1, b1);
      a2 = fmaxf(fmaxf(a2, b2), mn);
      if (b1 > a1 || (b1 == a1 && bi < ai)) { a1 = b1; ai = bi; }
    }
    if (c16 == 0) {
      int row = wr * 64 + (slot >> 2) * 16 + q * 4 + (slot & 3);
      rS1[wc * 128 + row] = a1; rS2[wc * 128 + row] = a2; rI1[wc * 128 + row] = ai;
    }
  }
  __syncthreads();
  if (tid < 128) {
    float a1 = rS1[tid], a2 = rS2[tid]; int ai = rI1[tid];
    #pragma unroll
    for (int gq = 1; gq < 4; ++gq) {
      float b1 = rS1[gq * 128 + tid], b2 = rS2[gq * 128 + tid]; int bi = rI1[gq * 128 + tid];
      float mn = fminf(a1, b1);
      a2 = fmaxf(fmaxf(a2, b2), mn);
      if (b1 > a1 || (b1 == a1 && bi < ai)) { a1 = b1; ai = bi; }
    }
    const int row = n0 + tid;
    out_ind[row] = (float)ai;
    if (a1 - a2 < EPS) {
      int p = atomicAdd(cnt, 1);
      list[p] = row;
      flags[row] = p + 1;
    } else {
      flags[row] = 0;
    }
  }
}

// ---------- cleanup: exact fp32 rescore of flagged rows (split 8 k-chunks) ----------
__global__ __launch_bounds__(256) void cleanup_kernel(const float* __restrict__ x,
                                                      const float* __restrict__ embed,
                                                      const float* __restrict__ esq,
                                                      const float* __restrict__ inv2,
                                                      const int* __restrict__ list,
                                                      const int* __restrict__ cnt,
                                                      float2* __restrict__ exact) {
  __shared__ float xr[DDIM];
  __shared__ float red_s[4];
  __shared__ int   red_i[4];
  const int rs = blockIdx.x & 31, kc = blockIdx.x >> 5;
  const int tid = threadIdx.x;
  const int lane = tid & 63, wid = tid >> 6;
  const int n = *cnt;
  for (int ii = rs; ii < n; ii += 32) {
    const int row = list[ii];
    __syncthreads();
    if (tid < 128) *(float4*)&xr[tid * 4] = *(const float4*)&x[(size_t)row * DDIM + tid * 4];
    __syncthreads();
    const float iv = inv2[row];
    float bs = -3e38f; int bi = 0;
    for (int cc = 0; cc < 2; ++cc) {
      const int code = kc * 512 + cc * 256 + tid;
      const float4* er = (const float4*)&embed[(size_t)code * DDIM];
      float acc = 0.f;
      for (int d = 0; d < DDIM / 4; ++d) {
        float4 e4 = er[d];
        float4 x4 = *(const float4*)&xr[d * 4];
        acc += x4.x * e4.x + x4.y * e4.y + x4.z * e4.z + x4.w * e4.w;
      }
      float sc = fmaf(acc, iv, -esq[code]);
      if (sc > bs || (sc == bs && code < bi)) { bs = sc; bi = code; }
    }
    #pragma unroll
    for (int off = 1; off < 64; off <<= 1) {
      float b1 = __shfl_xor(bs, off);
      int   b2 = __shfl_xor(bi, off);
      if (b1 > bs || (b1 == bs && b2 < bi)) { bs = b1; bi = b2; }
    }
    if (lane == 0) { red_s[wid] = bs; red_i[wid] = bi; }
    __syncthreads();
    if (tid == 0) {
      for (int ww = 1; ww < 4; ++ww)
        if (red_s[ww] > red_s[0] || (red_s[ww] == red_s[0] && red_i[ww] < red_i[0])) {
          red_s[0] = red_s[ww]; red_i[0] = red_i[ww];
        }
      exact[(size_t)ii * 8 + kc] = make_float2(red_s[0], (float)red_i[0]);
    }
  }
}

// ---------- gather + transpose (merges exact results for flagged rows) ----------
__global__ __launch_bounds__(256) void gather_kernel(const float* __restrict__ embed,
                                                     const int* __restrict__ flags,
                                                     const float2* __restrict__ exact,
                                                     float* __restrict__ out_ind,
                                                     float* __restrict__ out_q) {
  __shared__ int lidx[64];
  __shared__ float trans[64 * 65];
  const int n0 = blockIdx.x * 64;
  const int tid = threadIdx.x;
  if (tid < 64) {
    const int row = n0 + tid;
    const int f = flags[row];
    int idx;
    if (f) {
      float bsv = -3e38f; int bi = 0;
      const float2* e8 = &exact[(size_t)(f - 1) * 8];
      #pragma unroll
      for (int k = 0; k < 8; ++k) {
        float2 t = e8[k];
        int ci = (int)t.y;
        if (t.x > bsv || (t.x == bsv && ci < bi)) { bsv = t.x; bi = ci; }
      }
      idx = bi;
      out_ind[row] = (float)idx;
    } else {
      idx = (int)out_ind[row];
    }
    lidx[tid] = idx;
  }
  __syncthreads();
  const int bb = n0 >> 12;
  const int t0 = n0 & (TT - 1);
  const int w = tid >> 6, lane = tid & 63;
  for (int d0 = 0; d0 < DDIM; d0 += 64) {
    if (d0) __syncthreads();
    #pragma unroll
    for (int qq = 0; qq < 16; ++qq) {
      int tt2 = w * 16 + qq;
      int e = lidx[tt2];
      trans[lane * 65 + tt2] = embed[(size_t)e * DDIM + d0 + lane];
    }
    __syncthreads();
    #pragma unroll
    for (int qq = 0; qq < 4; ++qq) {
      int dl = (tid >> 4) * 4 + qq;
      int t4 = (tid & 15) * 4;
      float4 o;
      o.x = trans[dl * 65 + t4 + 0];
      o.y = trans[dl * 65 + t4 + 1];
      o.z = trans[dl * 65 + t4 + 2];
      o.w = trans[dl * 65 + t4 + 3];
      *(float4*)&out_q[((size_t)bb * DDIM + d0 + dl) * TT + t0 + t4] = o;
    }
  }
}

extern "C" void kernel_launch(void* const* d_in, const int* in_sizes, int n_in,
                              void* d_out, int out_size, void* d_ws, size_t ws_size,
                              hipStream_t stream) {
  const float* x     = (const float*)d_in[0];
  const float* embed = (const float*)d_in[1];
  char* ws = (char*)d_ws;
  short* xb      = (short*)(ws);                         // 33,554,432 B
  short* eb      = (short*)(ws + 33554432);              //  4,194,304 B
  float* esq     = (float*)(ws + 37748736);              //     16,384 B
  float* inv2    = (float*)(ws + 37765120);              //    131,072 B
  int* list      = (int*)(ws + 39993344);                //    131,072 B
  int* flags     = (int*)(ws + 40124416);                //    131,072 B
  float2* exact  = (float2*)(ws + 40255488);             //  2,097,152 B
  int* cnt       = (int*)(ws + 42352640);                //          4 B

  float* out_ind = (float*)d_out;
  float* out_q   = out_ind + NN;

  prep_kernel<<<KK / 4, 256, 0, stream>>>(embed, eb, esq, 0);
  prep_kernel<<<NN / 4, 256, 0, stream>>>(x, xb, inv2, 1);
  hipMemsetAsync(cnt, 0, 4, stream);
  vq_mfma<<<256, 512, 0, stream>>>(xb, eb, esq, inv2, out_ind, flags, list, cnt);
  cleanup_kernel<<<256, 256, 0, stream>>>(x, embed, esq, inv2, list, cnt, exact);
  gather_kernel<<<NN / 64, 256, 0, stream>>>(embed, flags, exact, out_ind, out_q);
}